// Round 1
// baseline (112.731 us; speedup 1.0000x reference)
//
#include <hip/hip_runtime.h>
#include <math.h>

// Problem constants (from reference): B=4, N=4096, H=16, D=64
#define BB 4
#define NN 4096
#define HH 16
#define DD 64

// One (b,n,h) "group" per 16 lanes; each lane owns 4 consecutive d (float4).
// Layouts: parent tensors [B,N,H,D] flat index = g*64 + d where g = (b*N+n)*H+h.
// Children:  K_c/V_c [B,2N,H,D]; children of node n are rows 2n and 2n+1:
//   idx = ((b*2N + 2n + c)*H + h)*D + d ; row step = H*D = 1024 floats.
__global__ __launch_bounds__(256) void hsa_kernel(
    const float* __restrict__ Qp,
    const float* __restrict__ Kp,
    const float* __restrict__ Vp,
    const float* __restrict__ Kc,
    const float* __restrict__ Vc,
    float* __restrict__ out)
{
    const int total_groups = BB * NN * HH;      // 262144
    const float sm_scale = 0.125f;              // 1/sqrt(64)

    const int tid     = blockIdx.x * blockDim.x + threadIdx.x;
    const int lane4   = tid & 15;               // lane within 16-lane group
    const int gstart  = tid >> 4;
    const int gstride = (gridDim.x * blockDim.x) >> 4;  // 32768 with 2048x256

    for (int g = gstart; g < total_groups; g += gstride) {
        const int h = g & (HH - 1);
        const int n = (g >> 4) & (NN - 1);
        const int b = g >> 16;                  // g / (N*H)

        const int poff = g * DD + lane4 * 4;    // parent flat offset (fits int)
        const int c0   = (((b * 2 * NN + 2 * n) * HH + h) * DD) + lane4 * 4;
        const int c1   = c0 + HH * DD;          // sibling child row

        const float4 q   = *reinterpret_cast<const float4*>(Qp + poff);
        const float4 kp  = *reinterpret_cast<const float4*>(Kp + poff);
        const float4 kc0 = *reinterpret_cast<const float4*>(Kc + c0);
        const float4 kc1 = *reinterpret_cast<const float4*>(Kc + c1);
        const float4 vp  = *reinterpret_cast<const float4*>(Vp + poff);
        const float4 vc0 = *reinterpret_cast<const float4*>(Vc + c0);
        const float4 vc1 = *reinterpret_cast<const float4*>(Vc + c1);

        float s0 = q.x*kp.x  + q.y*kp.y  + q.z*kp.z  + q.w*kp.w;
        float s1 = q.x*kc0.x + q.y*kc0.y + q.z*kc0.z + q.w*kc0.w;
        float s2 = q.x*kc1.x + q.y*kc1.y + q.z*kc1.z + q.w*kc1.w;

        // reduce partial dots across the 16-lane group (xor masks < 16 stay in-group)
        #pragma unroll
        for (int m = 8; m >= 1; m >>= 1) {
            s0 += __shfl_xor(s0, m);
            s1 += __shfl_xor(s1, m);
            s2 += __shfl_xor(s2, m);
        }
        s0 *= sm_scale; s1 *= sm_scale; s2 *= sm_scale;

        const float mx = fmaxf(fmaxf(s0, s1), s2);
        const float e0 = __expf(s0 - mx);
        const float e1 = __expf(s1 - mx);
        const float e2 = __expf(s2 - mx);
        const float inv = 1.0f / (e0 + e1 + e2 + 1e-9f);
        const float w0 = e0 * inv, w1 = e1 * inv, w2 = e2 * inv;

        float4 o;
        o.x = w0*vp.x + w1*vc0.x + w2*vc1.x;
        o.y = w0*vp.y + w1*vc0.y + w2*vc1.y;
        o.z = w0*vp.z + w1*vc0.z + w2*vc1.z;
        o.w = w0*vp.w + w1*vc0.w + w2*vc1.w;
        *reinterpret_cast<float4*>(out + poff) = o;
    }
}

extern "C" void kernel_launch(void* const* d_in, const int* in_sizes, int n_in,
                              void* d_out, int out_size, void* d_ws, size_t ws_size,
                              hipStream_t stream) {
    const float* Qp = (const float*)d_in[0];
    const float* Kp = (const float*)d_in[1];
    const float* Vp = (const float*)d_in[2];
    const float* Kc = (const float*)d_in[3];
    const float* Vc = (const float*)d_in[4];
    float* out = (float*)d_out;

    // 262144 groups * 16 lanes = 4,194,304 lane-slots; 2048 blocks x 256 thr
    // -> each thread grid-strides 8 groups (evenly divisible, wave-uniform).
    dim3 grid(2048), block(256);
    hipLaunchKernelGGL(hsa_kernel, grid, block, 0, stream, Qp, Kp, Vp, Kc, Vc, out);
}

// Round 3
// 105.761 us; speedup vs baseline: 1.0659x; 1.0659x over previous
//
#include <hip/hip_runtime.h>
#include <math.h>

// Problem constants (from reference): B=4, N=4096, H=16, D=64
#define BB 4
#define NN 4096
#define HH 16
#define DD 64

// Launch geometry is FIXED so the grid-stride is a compile-time constant and
// the loop fully unrolls (8 groups/thread, processed 2 per iteration with all
// loads issued up front -> ~2x memory-level parallelism vs round 1).
#define GRID_BLOCKS 2048
#define BLOCK_THREADS 256
#define GSTRIDE ((GRID_BLOCKS * BLOCK_THREADS) >> 4)   // 32768 groups
#define TOTAL_GROUPS (BB * NN * HH)                     // 262144
#define ITERS (TOTAL_GROUPS / GSTRIDE)                  // 8

// clang-native 16B vector: works with __builtin_nontemporal_store
typedef float f32x4 __attribute__((ext_vector_type(4)));

__global__ __launch_bounds__(BLOCK_THREADS) void hsa_kernel(
    const float* __restrict__ Qp,
    const float* __restrict__ Kp,
    const float* __restrict__ Vp,
    const float* __restrict__ Kc,
    const float* __restrict__ Vc,
    float* __restrict__ out)
{
    const float sm_scale = 0.125f;              // 1/sqrt(64)

    const int tid    = blockIdx.x * blockDim.x + threadIdx.x;
    const int lane4  = tid & 15;                // lane within 16-lane group
    const int gstart = tid >> 4;

    #pragma unroll
    for (int k = 0; k < ITERS; k += 2) {
        const int ga = gstart + k * GSTRIDE;
        const int gb = ga + GSTRIDE;

        // ---- group A offsets ----
        const int ha = ga & (HH - 1);
        const int na = (ga >> 4) & (NN - 1);
        const int ba = ga >> 16;
        const int pa = ga * DD + lane4 * 4;
        const int a0 = (((ba * 2 * NN + 2 * na) * HH + ha) * DD) + lane4 * 4;
        const int a1 = a0 + HH * DD;
        // ---- group B offsets ----
        const int hb = gb & (HH - 1);
        const int nb = (gb >> 4) & (NN - 1);
        const int bb = gb >> 16;
        const int pb = gb * DD + lane4 * 4;
        const int b0 = (((bb * 2 * NN + 2 * nb) * HH + hb) * DD) + lane4 * 4;
        const int b1 = b0 + HH * DD;

        // ---- issue ALL 14 loads before any dependent compute ----
        const f32x4 qa   = *reinterpret_cast<const f32x4*>(Qp + pa);
        const f32x4 kpa  = *reinterpret_cast<const f32x4*>(Kp + pa);
        const f32x4 kc0a = *reinterpret_cast<const f32x4*>(Kc + a0);
        const f32x4 kc1a = *reinterpret_cast<const f32x4*>(Kc + a1);
        const f32x4 vpa  = *reinterpret_cast<const f32x4*>(Vp + pa);
        const f32x4 vc0a = *reinterpret_cast<const f32x4*>(Vc + a0);
        const f32x4 vc1a = *reinterpret_cast<const f32x4*>(Vc + a1);

        const f32x4 qb   = *reinterpret_cast<const f32x4*>(Qp + pb);
        const f32x4 kpb  = *reinterpret_cast<const f32x4*>(Kp + pb);
        const f32x4 kc0b = *reinterpret_cast<const f32x4*>(Kc + b0);
        const f32x4 kc1b = *reinterpret_cast<const f32x4*>(Kc + b1);
        const f32x4 vpb  = *reinterpret_cast<const f32x4*>(Vp + pb);
        const f32x4 vc0b = *reinterpret_cast<const f32x4*>(Vc + b0);
        const f32x4 vc1b = *reinterpret_cast<const f32x4*>(Vc + b1);

        // ---- group A score partials ----
        float s0a = qa.x*kpa.x  + qa.y*kpa.y  + qa.z*kpa.z  + qa.w*kpa.w;
        float s1a = qa.x*kc0a.x + qa.y*kc0a.y + qa.z*kc0a.z + qa.w*kc0a.w;
        float s2a = qa.x*kc1a.x + qa.y*kc1a.y + qa.z*kc1a.z + qa.w*kc1a.w;
        // ---- group B score partials (interleaved chains) ----
        float s0b = qb.x*kpb.x  + qb.y*kpb.y  + qb.z*kpb.z  + qb.w*kpb.w;
        float s1b = qb.x*kc0b.x + qb.y*kc0b.y + qb.z*kc0b.z + qb.w*kc0b.w;
        float s2b = qb.x*kc1b.x + qb.y*kc1b.y + qb.z*kc1b.z + qb.w*kc1b.w;

        #pragma unroll
        for (int m = 8; m >= 1; m >>= 1) {
            s0a += __shfl_xor(s0a, m);
            s1a += __shfl_xor(s1a, m);
            s2a += __shfl_xor(s2a, m);
            s0b += __shfl_xor(s0b, m);
            s1b += __shfl_xor(s1b, m);
            s2b += __shfl_xor(s2b, m);
        }

        s0a *= sm_scale; s1a *= sm_scale; s2a *= sm_scale;
        const float mxa = fmaxf(fmaxf(s0a, s1a), s2a);
        const float e0a = __expf(s0a - mxa);
        const float e1a = __expf(s1a - mxa);
        const float e2a = __expf(s2a - mxa);
        const float iva = 1.0f / (e0a + e1a + e2a + 1e-9f);
        const float w0a = e0a * iva, w1a = e1a * iva, w2a = e2a * iva;

        s0b *= sm_scale; s1b *= sm_scale; s2b *= sm_scale;
        const float mxb = fmaxf(fmaxf(s0b, s1b), s2b);
        const float e0b = __expf(s0b - mxb);
        const float e1b = __expf(s1b - mxb);
        const float e2b = __expf(s2b - mxb);
        const float ivb = 1.0f / (e0b + e1b + e2b + 1e-9f);
        const float w0b = e0b * ivb, w1b = e1b * ivb, w2b = e2b * ivb;

        f32x4 oa, ob;
        oa.x = w0a*vpa.x + w1a*vc0a.x + w2a*vc1a.x;
        oa.y = w0a*vpa.y + w1a*vc0a.y + w2a*vc1a.y;
        oa.z = w0a*vpa.z + w1a*vc0a.z + w2a*vc1a.z;
        oa.w = w0a*vpa.w + w1a*vc0a.w + w2a*vc1a.w;
        ob.x = w0b*vpb.x + w1b*vc0b.x + w2b*vc1b.x;
        ob.y = w0b*vpb.y + w1b*vc0b.y + w2b*vc1b.y;
        ob.z = w0b*vpb.z + w1b*vc0b.z + w2b*vc1b.z;
        ob.w = w0b*vpb.w + w1b*vc0b.w + w2b*vc1b.w;

        // Nontemporal stores: output is write-once, never read — don't let it
        // displace input lines from L2/L3 (replay residency is worth ~200 MB).
        __builtin_nontemporal_store(oa, reinterpret_cast<f32x4*>(out + pa));
        __builtin_nontemporal_store(ob, reinterpret_cast<f32x4*>(out + pb));
    }
}

extern "C" void kernel_launch(void* const* d_in, const int* in_sizes, int n_in,
                              void* d_out, int out_size, void* d_ws, size_t ws_size,
                              hipStream_t stream) {
    const float* Qp = (const float*)d_in[0];
    const float* Kp = (const float*)d_in[1];
    const float* Vp = (const float*)d_in[2];
    const float* Kc = (const float*)d_in[3];
    const float* Vc = (const float*)d_in[4];
    float* out = (float*)d_out;

    dim3 grid(GRID_BLOCKS), block(BLOCK_THREADS);
    hipLaunchKernelGGL(hsa_kernel, grid, block, 0, stream, Qp, Kp, Vp, Kc, Vc, out);
}

// Round 4
// 103.776 us; speedup vs baseline: 1.0863x; 1.0191x over previous
//
#include <hip/hip_runtime.h>
#include <math.h>

// Problem constants (from reference): B=4, N=4096, H=16, D=64
#define BB 4
#define NN 4096
#define HH 16
#define DD 64

#define GRID_BLOCKS 2048
#define BLOCK_THREADS 256
#define GSTRIDE ((GRID_BLOCKS * BLOCK_THREADS) >> 4)   // 32768 groups
#define TOTAL_GROUPS (BB * NN * HH)                     // 262144
#define ITERS (TOTAL_GROUPS / GSTRIDE)                  // 8
#define UNROLL 4                                        // groups per chunk

// clang-native 16B vector: works with __builtin_nontemporal_store
typedef float f32x4 __attribute__((ext_vector_type(4)));

// min 3 waves/EU -> VGPR cap ~168: enough to keep 28 loads (112 VGPR) in
// flight per wave. Round 3 showed the default regalloc throttles to 36 VGPR
// and serializes the loads — we trade occupancy (58%->~38%) for ~4x MLP.
__global__ __launch_bounds__(BLOCK_THREADS, 3) void hsa_kernel(
    const float* __restrict__ Qp,
    const float* __restrict__ Kp,
    const float* __restrict__ Vp,
    const float* __restrict__ Kc,
    const float* __restrict__ Vc,
    float* __restrict__ out)
{
    const float sm_scale = 0.125f;              // 1/sqrt(64)

    const int tid    = blockIdx.x * blockDim.x + threadIdx.x;
    const int lane4  = tid & 15;                // lane within 16-lane group
    const int gstart = tid >> 4;

    #pragma unroll
    for (int k = 0; k < ITERS; k += UNROLL) {
        f32x4 q[UNROLL], kp[UNROLL], kc0[UNROLL], kc1[UNROLL];
        f32x4 vp[UNROLL], vc0[UNROLL], vc1[UNROLL];
        int poff[UNROLL];

        // ---- issue ALL 28 loads before any dependent compute ----
        #pragma unroll
        for (int j = 0; j < UNROLL; ++j) {
            const int g = gstart + (k + j) * GSTRIDE;
            const int h = g & (HH - 1);
            const int n = (g >> 4) & (NN - 1);
            const int b = g >> 16;
            const int p = g * DD + lane4 * 4;
            const int c0 = (((b * 2 * NN + 2 * n) * HH + h) * DD) + lane4 * 4;
            const int c1 = c0 + HH * DD;
            poff[j] = p;
            q[j]   = *reinterpret_cast<const f32x4*>(Qp + p);
            kp[j]  = *reinterpret_cast<const f32x4*>(Kp + p);
            kc0[j] = *reinterpret_cast<const f32x4*>(Kc + c0);
            kc1[j] = *reinterpret_cast<const f32x4*>(Kc + c1);
            vp[j]  = *reinterpret_cast<const f32x4*>(Vp + p);
            vc0[j] = *reinterpret_cast<const f32x4*>(Vc + c0);
            vc1[j] = *reinterpret_cast<const f32x4*>(Vc + c1);
        }
        // Pin the schedule: loads above may NOT be sunk below this point.
        __builtin_amdgcn_sched_barrier(0);

        float s0[UNROLL], s1[UNROLL], s2[UNROLL];
        #pragma unroll
        for (int j = 0; j < UNROLL; ++j) {
            s0[j] = q[j].x*kp[j].x  + q[j].y*kp[j].y  + q[j].z*kp[j].z  + q[j].w*kp[j].w;
            s1[j] = q[j].x*kc0[j].x + q[j].y*kc0[j].y + q[j].z*kc0[j].z + q[j].w*kc0[j].w;
            s2[j] = q[j].x*kc1[j].x + q[j].y*kc1[j].y + q[j].z*kc1[j].z + q[j].w*kc1[j].w;
        }

        // 12 independent butterfly chains interleaved -> ds latency pipelines
        #pragma unroll
        for (int m = 8; m >= 1; m >>= 1) {
            #pragma unroll
            for (int j = 0; j < UNROLL; ++j) {
                s0[j] += __shfl_xor(s0[j], m);
                s1[j] += __shfl_xor(s1[j], m);
                s2[j] += __shfl_xor(s2[j], m);
            }
        }

        #pragma unroll
        for (int j = 0; j < UNROLL; ++j) {
            const float t0 = s0[j] * sm_scale;
            const float t1 = s1[j] * sm_scale;
            const float t2 = s2[j] * sm_scale;
            const float mx = fmaxf(fmaxf(t0, t1), t2);
            const float e0 = __expf(t0 - mx);
            const float e1 = __expf(t1 - mx);
            const float e2 = __expf(t2 - mx);
            const float inv = 1.0f / (e0 + e1 + e2 + 1e-9f);
            const float w0 = e0 * inv, w1 = e1 * inv, w2 = e2 * inv;

            f32x4 o;
            o.x = w0*vp[j].x + w1*vc0[j].x + w2*vc1[j].x;
            o.y = w0*vp[j].y + w1*vc0[j].y + w2*vc1[j].y;
            o.z = w0*vp[j].z + w1*vc0[j].z + w2*vc1[j].z;
            o.w = w0*vp[j].w + w1*vc0[j].w + w2*vc1[j].w;
            // write-once output: nontemporal, don't pollute L2/L3
            __builtin_nontemporal_store(o, reinterpret_cast<f32x4*>(out + poff[j]));
        }
    }
}

extern "C" void kernel_launch(void* const* d_in, const int* in_sizes, int n_in,
                              void* d_out, int out_size, void* d_ws, size_t ws_size,
                              hipStream_t stream) {
    const float* Qp = (const float*)d_in[0];
    const float* Kp = (const float*)d_in[1];
    const float* Vp = (const float*)d_in[2];
    const float* Kc = (const float*)d_in[3];
    const float* Vc = (const float*)d_in[4];
    float* out = (float*)d_out;

    dim3 grid(GRID_BLOCKS), block(BLOCK_THREADS);
    hipLaunchKernelGGL(hsa_kernel, grid, block, 0, stream, Qp, Kp, Vp, Kc, Vc, out);
}